// Round 1
// baseline (94.587 us; speedup 1.0000x reference)
//
#include <hip/hip_runtime.h>
#include <cstdint>

#define NK 16384
#define NB 4096
#define NM 256
#define LOG2E 1.4426950408889634f

typedef __attribute__((ext_vector_type(8))) short short8;
typedef __attribute__((ext_vector_type(4))) float floatx4;

#if __has_builtin(__builtin_amdgcn_exp2f)
#define EXP2F(x) __builtin_amdgcn_exp2f(x)
#else
#define EXP2F(x) exp2f(x)
#endif

// Static device scratch (avoids any ws_size assumption):
// bf16 copy of x_basis [4096][256] row-major, and per-center {W[n], ||c_n||^2 * log2e}.
__device__ unsigned short g_xb[NB * NM];   // 2 MB
__device__ float2 g_wc[NB];                // 32 KB

__device__ __forceinline__ unsigned short f2bf(float f) {
    unsigned int u = __float_as_uint(f);
    u += 0x7FFFu + ((u >> 16) & 1u);       // RTN-even
    return (unsigned short)(u >> 16);
}

// One wave per x_basis row: convert 256 fp32 -> bf16, compute ||c||^2.
__global__ __launch_bounds__(256) void rbf_prep(const float* __restrict__ xb,
                                                const float* __restrict__ W) {
    const int row  = blockIdx.x * 4 + (threadIdx.x >> 6);
    const int lane = threadIdx.x & 63;
    const float4 v = ((const float4*)(xb + row * NM))[lane];
    float ss = v.x * v.x + v.y * v.y + v.z * v.z + v.w * v.w;
    #pragma unroll
    for (int m = 1; m < 64; m <<= 1) ss += __shfl_xor(ss, m, 64);
    ushort4 o;
    o.x = f2bf(v.x); o.y = f2bf(v.y); o.z = f2bf(v.z); o.w = f2bf(v.w);
    *(ushort4*)(g_xb + row * NM + lane * 4) = o;
    if (lane == 0) g_wc[row] = make_float2(W[row], ss * LOG2E);
}

// Stage one 32-center pair-tile (2 parities x 16 rows x 512B) into LDS buffer `bufidx`.
// global_load_lds: linear LDS dest (wave-uniform base + lane*16); bank-conflict swizzle
// applied on the GLOBAL source side (chunk ^= row&7) per m173 pattern.
#define STAGE(pairidx, bufidx)                                                        \
    {                                                                                 \
        _Pragma("unroll")                                                             \
        for (int j = 0; j < 2; ++j) {                                                 \
            const int idx = w * 2 + j;            /* 0..15 */                         \
            const int pp  = idx >> 3;             /* parity staged */                 \
            const int rc  = idx & 7;              /* 64-chunk group */                \
            const int q   = rc * 64 + lane;       /* chunk 0..511 within parity */    \
            const int rr  = q >> 5;               /* row 0..15 */                     \
            const int cc  = q & 31;               /* 16B chunk in row */              \
            const unsigned short* srcp = g_xb + ((pairidx) * 32 + pp * 16 + rr) * NM  \
                                              + ((cc ^ (rr & 7)) * 8);                \
            unsigned short* dstp = &Bt[bufidx][pp][rc * 512];                         \
            __builtin_amdgcn_global_load_lds(                                         \
                (const __attribute__((address_space(1))) void*)srcp,                  \
                (__attribute__((address_space(3))) void*)dstp, 16, 0, 0);             \
        }                                                                             \
    }

// 256 blocks (1/CU), 512 threads (8 waves = 2/SIMD).
// Block owns 64 sample-rows; wave w: row-tile (w&3), n-tile parity (w>>2).
__global__ __launch_bounds__(512, 2) void rbf_main(const float* __restrict__ x,
                                                   const float* __restrict__ bptr,
                                                   float* __restrict__ out) {
    __shared__ __align__(16) unsigned short Bt[2][2][16 * NM];  // [buf][parity] 8KB tiles
    __shared__ float xsl[64];          // ||x_row||^2 * log2e
    __shared__ float rowacc[2][64];    // per-parity row partials

    const int tid  = threadIdx.x;
    const int w    = tid >> 6;
    const int lane = tid & 63;
    const int wt   = w & 3;            // row-tile within block
    const int p    = w >> 2;           // n-tile parity
    const int r    = lane & 15;
    const int g    = lane >> 4;
    const int row0 = blockIdx.x * 64;

    // ---- prologue: hoist A fragments (full M=256) from global x, fp32->bf16 ----
    // A layout (16x16x32): lane holds A[lane&15][(lane>>4)*8 + j] -> contiguous 8 floats.
    const int arow = row0 + wt * 16 + r;
    const float4* xr4 = (const float4*)(x + arow * NM);
    short8 afrag[8];
    float ss = 0.f;
    #pragma unroll
    for (int s = 0; s < 8; ++s) {
        const float4 f0 = xr4[s * 8 + g * 2];
        const float4 f1 = xr4[s * 8 + g * 2 + 1];
        ss += f0.x * f0.x + f0.y * f0.y + f0.z * f0.z + f0.w * f0.w
            + f1.x * f1.x + f1.y * f1.y + f1.z * f1.z + f1.w * f1.w;
        short8 a;
        a[0] = (short)f2bf(f0.x); a[1] = (short)f2bf(f0.y);
        a[2] = (short)f2bf(f0.z); a[3] = (short)f2bf(f0.w);
        a[4] = (short)f2bf(f1.x); a[5] = (short)f2bf(f1.y);
        a[6] = (short)f2bf(f1.z); a[7] = (short)f2bf(f1.w);
        afrag[s] = a;
    }
    // per-row ||x||^2: combine the 4 k-groups (lanes differing in bits 4,5)
    ss += __shfl_xor(ss, 16, 64);
    ss += __shfl_xor(ss, 32, 64);
    if (p == 0 && g == 0) xsl[wt * 16 + r] = ss * LOG2E;

    STAGE(0, 0);
    __syncthreads();   // drains vmcnt(0): stage 0 complete, xsl visible

    // C/D rows for this lane: wt*16 + g*4 + {0..3}
    const float xs0 = xsl[wt * 16 + g * 4 + 0];
    const float xs1 = xsl[wt * 16 + g * 4 + 1];
    const float xs2 = xsl[wt * 16 + g * 4 + 2];
    const float xs3 = xsl[wt * 16 + g * 4 + 3];

    float ac0 = 0.f, ac1 = 0.f, ac2 = 0.f, ac3 = 0.f;

    for (int i = 0; i < 128; ++i) {
        const int buf = i & 1;
        // per-column {W, csq*log2e} for this lane's column (n-tile col = lane&15)
        const float2 wc = g_wc[(2 * i + p) * 16 + r];
        STAGE((i + 1) & 127, buf ^ 1);   // prefetch next pair-tile (2-phase schedule)

        // B fragments from LDS (swizzled read matches staged source permutation)
        const unsigned short* bp = &Bt[buf][p][0];
        short8 bfrag[8];
        #pragma unroll
        for (int s = 0; s < 8; ++s) {
            const int chunk = (s * 4 + g) ^ (r & 7);
            bfrag[s] = *(const short8*)(bp + r * 256 + chunk * 8);
        }
        floatx4 c = {0.f, 0.f, 0.f, 0.f};
        #pragma unroll
        for (int s = 0; s < 8; ++s)
            c = __builtin_amdgcn_mfma_f32_16x16x32_bf16(afrag[s], bfrag[s], c, 0, 0, 0);

        // phi = exp(-(xsq + csq - 2*cross)) = exp2(cross*2*log2e - xsl - csl); acc += W*phi
        const float nb = -wc.y;
        ac0 = fmaf(EXP2F(fmaf(c[0], 2.f * LOG2E, nb - xs0)), wc.x, ac0);
        ac1 = fmaf(EXP2F(fmaf(c[1], 2.f * LOG2E, nb - xs1)), wc.x, ac1);
        ac2 = fmaf(EXP2F(fmaf(c[2], 2.f * LOG2E, nb - xs2)), wc.x, ac2);
        ac3 = fmaf(EXP2F(fmaf(c[3], 2.f * LOG2E, nb - xs3)), wc.x, ac3);

        __syncthreads();   // stage for i+1 drained; buf safe to overwrite next iter
    }

    // reduce over the 16 column-lanes of each group
    #pragma unroll
    for (int m = 1; m < 16; m <<= 1) {
        ac0 += __shfl_xor(ac0, m, 64);
        ac1 += __shfl_xor(ac1, m, 64);
        ac2 += __shfl_xor(ac2, m, 64);
        ac3 += __shfl_xor(ac3, m, 64);
    }
    if (r == 0) {
        float* ra = &rowacc[p][wt * 16 + g * 4];
        ra[0] = ac0; ra[1] = ac1; ra[2] = ac2; ra[3] = ac3;
    }
    __syncthreads();

    if (tid < 64) {
        const float logit = rowacc[0][tid] + rowacc[1][tid] + bptr[0];
        out[row0 + tid] = 1.f / (1.f + EXP2F(-logit * LOG2E));
    }
}

extern "C" void kernel_launch(void* const* d_in, const int* in_sizes, int n_in,
                              void* d_out, int out_size, void* d_ws, size_t ws_size,
                              hipStream_t stream) {
    const float* x  = (const float*)d_in[0];   // [16384,256]
    const float* xb = (const float*)d_in[1];   // [4096,256]
    const float* W  = (const float*)d_in[2];   // [1,4096]
    const float* b  = (const float*)d_in[3];   // [1]
    float* out = (float*)d_out;                // [16384,1]

    rbf_prep<<<dim3(NB / 4), dim3(256), 0, stream>>>(xb, W);
    rbf_main<<<dim3(NK / 64), dim3(512), 0, stream>>>(x, b, out);
}

// Round 2
// 81.912 us; speedup vs baseline: 1.1547x; 1.1547x over previous
//
#include <hip/hip_runtime.h>
#include <cstdint>

#define NK 16384
#define NB 4096
#define NM 256
#define LOG2E 1.4426950408889634f
#define TWO_LOG2E 2.8853900817779268f

typedef __attribute__((ext_vector_type(8))) short short8;
typedef __attribute__((ext_vector_type(4))) float floatx4;

#if __has_builtin(__builtin_amdgcn_exp2f)
#define EXP2F(x) __builtin_amdgcn_exp2f(x)
#else
#define EXP2F(x) exp2f(x)
#endif

// Static device scratch: bf16 copy of x_basis [4096][256], per-center {W[n], ||c_n||^2*log2e}.
__device__ unsigned short g_xb[NB * NM];   // 2 MB (L2-resident per XCD)
__device__ float2 g_wc[NB];                // 32 KB

__device__ __forceinline__ unsigned short f2bf(float f) {
    unsigned int u = __float_as_uint(f);
    u += 0x7FFFu + ((u >> 16) & 1u);       // RTN-even
    return (unsigned short)(u >> 16);
}

// One wave per x_basis row: convert 256 fp32 -> bf16, compute ||c||^2 * log2e.
__global__ __launch_bounds__(256) void rbf_prep(const float* __restrict__ xb,
                                                const float* __restrict__ W) {
    const int row  = blockIdx.x * 4 + (threadIdx.x >> 6);
    const int lane = threadIdx.x & 63;
    const float4 v = ((const float4*)(xb + row * NM))[lane];
    float ss = v.x * v.x + v.y * v.y + v.z * v.z + v.w * v.w;
    #pragma unroll
    for (int m = 1; m < 64; m <<= 1) ss += __shfl_xor(ss, m, 64);
    ushort4 o;
    o.x = f2bf(v.x); o.y = f2bf(v.y); o.z = f2bf(v.z); o.w = f2bf(v.w);
    *(ushort4*)(g_xb + row * NM + lane * 4) = o;
    if (lane == 0) g_wc[row] = make_float2(W[row], ss * LOG2E);
}

// Stage one 16-center tile (16 x 256 bf16 = 8KB) into this wave's LDS buffer.
// LDS dest linear (HW: uniform base + lane*16); bank-conflict swizzle applied on the
// GLOBAL source side (chunk ^= row&7) per m173; ds_read applies the same involution.
#define STAGE(t, bufIdx)                                                              \
    {                                                                                 \
        _Pragma("unroll")                                                             \
        for (int j = 0; j < 8; ++j) {                                                 \
            const int q  = j * 64 + lane;      /* 16B-chunk index within tile */      \
            const int rr = q >> 5;             /* center row 0..15 */                 \
            const int cc = q & 31;             /* 16B chunk within row */             \
            const unsigned short* srcp =                                              \
                g_xb + (n0 + (t) * 16 + rr) * NM + ((cc ^ (rr & 7)) * 8);             \
            unsigned short* dstp = &Bt[w][bufIdx][j * 512];                           \
            __builtin_amdgcn_global_load_lds(                                         \
                (const __attribute__((address_space(1))) void*)srcp,                  \
                (__attribute__((address_space(3))) void*)dstp, 16, 0, 0);             \
        }                                                                             \
    }

// One 16-center tile: 8 ds_read_b128 -> 32 MFMA (4 row-tiles) -> fused exp/W epilogue.
#define COMPUTE(bufIdx, wcv)                                                          \
    {                                                                                 \
        const unsigned short* bp = &Bt[w][bufIdx][0];                                 \
        floatx4 c0 = {0.f,0.f,0.f,0.f}, c1 = {0.f,0.f,0.f,0.f};                       \
        floatx4 c2 = {0.f,0.f,0.f,0.f}, c3 = {0.f,0.f,0.f,0.f};                       \
        _Pragma("unroll")                                                             \
        for (int s = 0; s < 8; ++s) {                                                 \
            const short8 b =                                                          \
                *(const short8*)(bp + r * 256 + (((s * 4 + g) ^ (r & 7)) * 8));       \
            c0 = __builtin_amdgcn_mfma_f32_16x16x32_bf16(afrag[0][s], b, c0, 0,0,0);  \
            c1 = __builtin_amdgcn_mfma_f32_16x16x32_bf16(afrag[1][s], b, c1, 0,0,0);  \
            c2 = __builtin_amdgcn_mfma_f32_16x16x32_bf16(afrag[2][s], b, c2, 0,0,0);  \
            c3 = __builtin_amdgcn_mfma_f32_16x16x32_bf16(afrag[3][s], b, c3, 0,0,0);  \
        }                                                                             \
        const float nb  = -(wcv).y;                                                   \
        const float wgt = (wcv).x;                                                    \
        _Pragma("unroll")                                                             \
        for (int j = 0; j < 4; ++j) {                                                 \
            ac[0][j] = fmaf(EXP2F(fmaf(c0[j], TWO_LOG2E, nb - xsr[0][j])), wgt, ac[0][j]); \
            ac[1][j] = fmaf(EXP2F(fmaf(c1[j], TWO_LOG2E, nb - xsr[1][j])), wgt, ac[1][j]); \
            ac[2][j] = fmaf(EXP2F(fmaf(c2[j], TWO_LOG2E, nb - xsr[2][j])), wgt, ac[2][j]); \
            ac[3][j] = fmaf(EXP2F(fmaf(c3[j], TWO_LOG2E, nb - xsr[3][j])), wgt, ac[3][j]); \
        }                                                                             \
    }

// 256 blocks (1/CU), 512 threads (8 waves). Block owns 64 rows; wave w owns ALL
// 4 row-tiles (A in registers) x centers [w*512, (w+1)*512). No main-loop barriers:
// each wave stages/reads only its own LDS region; counted vmcnt(9) pipelines.
__global__ __launch_bounds__(512, 2) void rbf_main(const float* __restrict__ x,
                                                   const float* __restrict__ bptr,
                                                   float* __restrict__ out) {
    __shared__ __align__(16) unsigned short Bt[8][2][16 * NM];  // 128 KB
    __shared__ float xsl[64];
    __shared__ float rowacc[8][64];

    const int tid  = threadIdx.x;
    const int w    = tid >> 6;
    const int lane = tid & 63;
    const int r    = lane & 15;
    const int g    = lane >> 4;
    const int row0 = blockIdx.x * 64;
    const int n0   = w * 512;

    // ---- A prologue: 64 rows x 256 M -> bf16 fragments in 128 VGPRs ----
    short8 afrag[4][8];
    #pragma unroll
    for (int rt = 0; rt < 4; ++rt) {
        const float4* xr4 = (const float4*)(x + (row0 + rt * 16 + r) * NM);
        float ss = 0.f;
        #pragma unroll
        for (int s = 0; s < 8; ++s) {
            const float4 f0 = xr4[s * 8 + g * 2];
            const float4 f1 = xr4[s * 8 + g * 2 + 1];
            ss += f0.x * f0.x + f0.y * f0.y + f0.z * f0.z + f0.w * f0.w
                + f1.x * f1.x + f1.y * f1.y + f1.z * f1.z + f1.w * f1.w;
            short8 a;
            a[0] = (short)f2bf(f0.x); a[1] = (short)f2bf(f0.y);
            a[2] = (short)f2bf(f0.z); a[3] = (short)f2bf(f0.w);
            a[4] = (short)f2bf(f1.x); a[5] = (short)f2bf(f1.y);
            a[6] = (short)f2bf(f1.z); a[7] = (short)f2bf(f1.w);
            afrag[rt][s] = a;
        }
        ss += __shfl_xor(ss, 16, 64);
        ss += __shfl_xor(ss, 32, 64);
        if (w == 0 && g == 0) xsl[rt * 16 + r] = ss * LOG2E;
    }
    __syncthreads();

    // per-lane ||x||^2*log2e for this lane's C/D rows: rt*16 + g*4 + {0..3}
    float xsr[4][4];
    #pragma unroll
    for (int rt = 0; rt < 4; ++rt) {
        const float4 v = *(const float4*)&xsl[rt * 16 + g * 4];
        xsr[rt][0] = v.x; xsr[rt][1] = v.y; xsr[rt][2] = v.z; xsr[rt][3] = v.w;
    }

    float ac[4][4] = {};

    // prologue: tile 0 + wc 0 in flight (9 vmem ops outstanding at loop top)
    STAGE(0, 0);
    float2 wcA = g_wc[n0 + r];
    float2 wcB;

    #pragma unroll 1
    for (int i = 0; i < 32; i += 2) {
        // ---- iter i: consume buf0/wcA, prefetch tile i+1 -> buf1 ----
        wcB = g_wc[n0 + ((i + 1) & 31) * 16 + r];
        STAGE((i + 1) & 31, 1);
        asm volatile("s_waitcnt vmcnt(9)" ::: "memory");  // tile i + wc_i drained; 9 newest in flight
        __builtin_amdgcn_sched_barrier(0);
        COMPUTE(0, wcA);
        // ---- iter i+1: consume buf1/wcB, prefetch tile i+2 -> buf0 ----
        wcA = g_wc[n0 + ((i + 2) & 31) * 16 + r];
        STAGE((i + 2) & 31, 0);
        asm volatile("s_waitcnt vmcnt(9)" ::: "memory");
        __builtin_amdgcn_sched_barrier(0);
        COMPUTE(1, wcB);
    }

    // ---- reduce over the 16 column-lanes; combine 8 waves' N-partials ----
    #pragma unroll
    for (int rt = 0; rt < 4; ++rt) {
        #pragma unroll
        for (int j = 0; j < 4; ++j) {
            float v = ac[rt][j];
            v += __shfl_xor(v, 1, 64);
            v += __shfl_xor(v, 2, 64);
            v += __shfl_xor(v, 4, 64);
            v += __shfl_xor(v, 8, 64);
            if (r == 0) rowacc[w][rt * 16 + g * 4 + j] = v;
        }
    }
    __syncthreads();

    if (tid < 64) {
        float logit = bptr[0];
        #pragma unroll
        for (int ww = 0; ww < 8; ++ww) logit += rowacc[ww][tid];
        out[row0 + tid] = 1.f / (1.f + EXP2F(-logit * LOG2E));
    }
}

extern "C" void kernel_launch(void* const* d_in, const int* in_sizes, int n_in,
                              void* d_out, int out_size, void* d_ws, size_t ws_size,
                              hipStream_t stream) {
    const float* x  = (const float*)d_in[0];   // [16384,256]
    const float* xb = (const float*)d_in[1];   // [4096,256]
    const float* W  = (const float*)d_in[2];   // [1,4096]
    const float* b  = (const float*)d_in[3];   // [1]
    float* out = (float*)d_out;                // [16384,1]

    rbf_prep<<<dim3(NB / 4), dim3(256), 0, stream>>>(xb, W);
    rbf_main<<<dim3(NK / 64), dim3(512), 0, stream>>>(x, b, out);
}

// Round 3
// 81.894 us; speedup vs baseline: 1.1550x; 1.0002x over previous
//
#include <hip/hip_runtime.h>
#include <cstdint>

#define NK 16384
#define NB 4096
#define NM 256
#define LOG2E 1.4426950408889634f
#define TWO_LOG2E 2.8853900817779268f

typedef __attribute__((ext_vector_type(8))) short short8;
typedef __attribute__((ext_vector_type(4))) float floatx4;

#if __has_builtin(__builtin_amdgcn_exp2f)
#define EXP2F(x) __builtin_amdgcn_exp2f(x)
#else
#define EXP2F(x) exp2f(x)
#endif

// Static device scratch: bf16 copy of x_basis [4096][256], per-center {W[n], ||c_n||^2*log2e}.
__device__ unsigned short g_xb[NB * NM];   // 2 MB (L2-resident per XCD)
__device__ float2 g_wc[NB];                // 32 KB

__device__ __forceinline__ unsigned short f2bf(float f) {
    unsigned int u = __float_as_uint(f);
    u += 0x7FFFu + ((u >> 16) & 1u);       // RTN-even
    return (unsigned short)(u >> 16);
}

// One wave per x_basis row: convert 256 fp32 -> bf16, compute ||c||^2 * log2e.
__global__ __launch_bounds__(256) void rbf_prep(const float* __restrict__ xb,
                                                const float* __restrict__ W) {
    const int row  = blockIdx.x * 4 + (threadIdx.x >> 6);
    const int lane = threadIdx.x & 63;
    const float4 v = ((const float4*)(xb + row * NM))[lane];
    float ss = v.x * v.x + v.y * v.y + v.z * v.z + v.w * v.w;
    #pragma unroll
    for (int m = 1; m < 64; m <<= 1) ss += __shfl_xor(ss, m, 64);
    ushort4 o;
    o.x = f2bf(v.x); o.y = f2bf(v.y); o.z = f2bf(v.z); o.w = f2bf(v.w);
    *(ushort4*)(g_xb + row * NM + lane * 4) = o;
    if (lane == 0) g_wc[row] = make_float2(W[row], ss * LOG2E);
}

// Stage one 16-center tile (16 x 256 bf16 = 8KB) into this wave's LDS buffer.
// LDS dest linear (HW: uniform base + lane*16); bank-conflict swizzle applied on the
// GLOBAL source side (chunk ^= row&7) per m173; ds_read applies the same involution.
#define STAGE(t, bufIdx)                                                              \
    {                                                                                 \
        _Pragma("unroll")                                                             \
        for (int j = 0; j < 8; ++j) {                                                 \
            const int q  = j * 64 + lane;      /* 16B-chunk index within tile */      \
            const int rr = q >> 5;             /* center row 0..15 */                 \
            const int cc = q & 31;             /* 16B chunk within row */             \
            const unsigned short* srcp =                                              \
                g_xb + (n0 + (t) * 16 + rr) * NM + ((cc ^ (rr & 7)) * 8);             \
            unsigned short* dstp = &Bt[w][bufIdx][j * 512];                           \
            __builtin_amdgcn_global_load_lds(                                         \
                (const __attribute__((address_space(1))) void*)srcp,                  \
                (__attribute__((address_space(3))) void*)dstp, 16, 0, 0);             \
        }                                                                             \
    }

// One 16-center tile: 8 ds_read_b128 -> 32 MFMA (4 row-tiles) -> fused exp/W epilogue.
#define COMPUTE(bufIdx, wcv)                                                          \
    {                                                                                 \
        const unsigned short* bp = &Bt[w][bufIdx][0];                                 \
        floatx4 c0 = {0.f,0.f,0.f,0.f}, c1 = {0.f,0.f,0.f,0.f};                       \
        floatx4 c2 = {0.f,0.f,0.f,0.f}, c3 = {0.f,0.f,0.f,0.f};                       \
        _Pragma("unroll")                                                             \
        for (int s = 0; s < 8; ++s) {                                                 \
            const short8 b =                                                          \
                *(const short8*)(bp + r * 256 + (((s * 4 + g) ^ (r & 7)) * 8));       \
            c0 = __builtin_amdgcn_mfma_f32_16x16x32_bf16(afrag[0][s], b, c0, 0,0,0);  \
            c1 = __builtin_amdgcn_mfma_f32_16x16x32_bf16(afrag[1][s], b, c1, 0,0,0);  \
            c2 = __builtin_amdgcn_mfma_f32_16x16x32_bf16(afrag[2][s], b, c2, 0,0,0);  \
            c3 = __builtin_amdgcn_mfma_f32_16x16x32_bf16(afrag[3][s], b, c3, 0,0,0);  \
        }                                                                             \
        const float nb  = -(wcv).y;                                                   \
        const float wgt = (wcv).x;                                                    \
        _Pragma("unroll")                                                             \
        for (int j = 0; j < 4; ++j) {                                                 \
            ac[0][j] = fmaf(EXP2F(fmaf(c0[j], TWO_LOG2E, nb - xsr[0][j])), wgt, ac[0][j]); \
            ac[1][j] = fmaf(EXP2F(fmaf(c1[j], TWO_LOG2E, nb - xsr[1][j])), wgt, ac[1][j]); \
            ac[2][j] = fmaf(EXP2F(fmaf(c2[j], TWO_LOG2E, nb - xsr[2][j])), wgt, ac[2][j]); \
            ac[3][j] = fmaf(EXP2F(fmaf(c3[j], TWO_LOG2E, nb - xsr[3][j])), wgt, ac[3][j]); \
        }                                                                             \
    }

// 256 blocks (1/CU), 512 threads (8 waves). Block owns 64 rows; wave w owns ALL
// 4 row-tiles (A in registers) x centers [w*512, (w+1)*512). No main-loop barriers:
// each wave stages/reads only its own LDS region; counted vmcnt(9) pipelines.
// launch_bounds(512,1): LDS (130KB) already caps at 1 block/CU = 2 waves/SIMD, which
// permits 256 VGPR/wave. The (512,2) bound made the allocator cap at 128 and spill
// ~80 regs (R2: WRITE_SIZE=66MB scratch traffic). (512,1) lets it take ~240.
__global__ __launch_bounds__(512, 1) void rbf_main(const float* __restrict__ x,
                                                   const float* __restrict__ bptr,
                                                   float* __restrict__ out) {
    __shared__ __align__(16) unsigned short Bt[8][2][16 * NM];  // 128 KB
    __shared__ float xsl[64];
    __shared__ float rowacc[8][64];

    const int tid  = threadIdx.x;
    const int w    = tid >> 6;
    const int lane = tid & 63;
    const int r    = lane & 15;
    const int g    = lane >> 4;
    const int row0 = blockIdx.x * 64;
    const int n0   = w * 512;

    // ---- A prologue: 64 rows x 256 M -> bf16 fragments in 128 VGPRs ----
    short8 afrag[4][8];
    #pragma unroll
    for (int rt = 0; rt < 4; ++rt) {
        const float4* xr4 = (const float4*)(x + (row0 + rt * 16 + r) * NM);
        float ss = 0.f;
        #pragma unroll
        for (int s = 0; s < 8; ++s) {
            const float4 f0 = xr4[s * 8 + g * 2];
            const float4 f1 = xr4[s * 8 + g * 2 + 1];
            ss += f0.x * f0.x + f0.y * f0.y + f0.z * f0.z + f0.w * f0.w
                + f1.x * f1.x + f1.y * f1.y + f1.z * f1.z + f1.w * f1.w;
            short8 a;
            a[0] = (short)f2bf(f0.x); a[1] = (short)f2bf(f0.y);
            a[2] = (short)f2bf(f0.z); a[3] = (short)f2bf(f0.w);
            a[4] = (short)f2bf(f1.x); a[5] = (short)f2bf(f1.y);
            a[6] = (short)f2bf(f1.z); a[7] = (short)f2bf(f1.w);
            afrag[rt][s] = a;
        }
        ss += __shfl_xor(ss, 16, 64);
        ss += __shfl_xor(ss, 32, 64);
        if (w == 0 && g == 0) xsl[rt * 16 + r] = ss * LOG2E;
    }
    __syncthreads();

    // per-lane ||x||^2*log2e for this lane's C/D rows: rt*16 + g*4 + {0..3}
    float xsr[4][4];
    #pragma unroll
    for (int rt = 0; rt < 4; ++rt) {
        const float4 v = *(const float4*)&xsl[rt * 16 + g * 4];
        xsr[rt][0] = v.x; xsr[rt][1] = v.y; xsr[rt][2] = v.z; xsr[rt][3] = v.w;
    }

    float ac[4][4] = {};

    // prologue: tile 0 + wc 0 in flight (9 vmem ops outstanding at loop top)
    STAGE(0, 0);
    float2 wcA = g_wc[n0 + r];
    float2 wcB;

    #pragma unroll 1
    for (int i = 0; i < 32; i += 2) {
        // ---- iter i: consume buf0/wcA, prefetch tile i+1 -> buf1 ----
        wcB = g_wc[n0 + ((i + 1) & 31) * 16 + r];
        STAGE((i + 1) & 31, 1);
        asm volatile("s_waitcnt vmcnt(9)" ::: "memory");  // tile i + wc_i drained; 9 newest in flight
        __builtin_amdgcn_sched_barrier(0);
        COMPUTE(0, wcA);
        // ---- iter i+1: consume buf1/wcB, prefetch tile i+2 -> buf0 ----
        wcA = g_wc[n0 + ((i + 2) & 31) * 16 + r];
        STAGE((i + 2) & 31, 0);
        asm volatile("s_waitcnt vmcnt(9)" ::: "memory");
        __builtin_amdgcn_sched_barrier(0);
        COMPUTE(1, wcB);
    }

    // ---- reduce over the 16 column-lanes; combine 8 waves' N-partials ----
    #pragma unroll
    for (int rt = 0; rt < 4; ++rt) {
        #pragma unroll
        for (int j = 0; j < 4; ++j) {
            float v = ac[rt][j];
            v += __shfl_xor(v, 1, 64);
            v += __shfl_xor(v, 2, 64);
            v += __shfl_xor(v, 4, 64);
            v += __shfl_xor(v, 8, 64);
            if (r == 0) rowacc[w][rt * 16 + g * 4 + j] = v;
        }
    }
    __syncthreads();

    if (tid < 64) {
        float logit = bptr[0];
        #pragma unroll
        for (int ww = 0; ww < 8; ++ww) logit += rowacc[ww][tid];
        out[row0 + tid] = 1.f / (1.f + EXP2F(-logit * LOG2E));
    }
}

extern "C" void kernel_launch(void* const* d_in, const int* in_sizes, int n_in,
                              void* d_out, int out_size, void* d_ws, size_t ws_size,
                              hipStream_t stream) {
    const float* x  = (const float*)d_in[0];   // [16384,256]
    const float* xb = (const float*)d_in[1];   // [4096,256]
    const float* W  = (const float*)d_in[2];   // [1,4096]
    const float* b  = (const float*)d_in[3];   // [1]
    float* out = (float*)d_out;                // [16384,1]

    rbf_prep<<<dim3(NB / 4), dim3(256), 0, stream>>>(xb, W);
    rbf_main<<<dim3(NK / 64), dim3(512), 0, stream>>>(x, b, out);
}

// Round 4
// 81.523 us; speedup vs baseline: 1.1602x; 1.0045x over previous
//
#include <hip/hip_runtime.h>
#include <cstdint>

#define NK 16384
#define NB 4096
#define NM 256
#define LOG2E 1.4426950408889634f
#define TWO_LOG2E 2.8853900817779268f

typedef __attribute__((ext_vector_type(8))) short short8;
typedef __attribute__((ext_vector_type(4))) float floatx4;

#if __has_builtin(__builtin_amdgcn_exp2f)
#define EXP2F(x) __builtin_amdgcn_exp2f(x)
#else
#define EXP2F(x) exp2f(x)
#endif

// Static device scratch: bf16 copy of x_basis [4096][256], per-center {W[n], ||c_n||^2*log2e}.
__device__ unsigned short g_xb[NB * NM];   // 2 MB (L2-resident per XCD)
__device__ float2 g_wc[NB];                // 32 KB

__device__ __forceinline__ unsigned short f2bf(float f) {
    unsigned int u = __float_as_uint(f);
    u += 0x7FFFu + ((u >> 16) & 1u);       // RTN-even
    return (unsigned short)(u >> 16);
}

// One wave per x_basis row: convert 256 fp32 -> bf16, compute ||c||^2 * log2e.
__global__ __launch_bounds__(256) void rbf_prep(const float* __restrict__ xb,
                                                const float* __restrict__ W) {
    const int row  = blockIdx.x * 4 + (threadIdx.x >> 6);
    const int lane = threadIdx.x & 63;
    const float4 v = ((const float4*)(xb + row * NM))[lane];
    float ss = v.x * v.x + v.y * v.y + v.z * v.z + v.w * v.w;
    #pragma unroll
    for (int m = 1; m < 64; m <<= 1) ss += __shfl_xor(ss, m, 64);
    ushort4 o;
    o.x = f2bf(v.x); o.y = f2bf(v.y); o.z = f2bf(v.z); o.w = f2bf(v.w);
    *(ushort4*)(g_xb + row * NM + lane * 4) = o;
    if (lane == 0) g_wc[row] = make_float2(W[row], ss * LOG2E);
}

// Stage one 16-center tile (16 x 256 bf16 = 8KB) into this wave's LDS buffer.
// LDS dest linear (HW: uniform base + lane*16); bank-conflict swizzle applied on the
// GLOBAL source side (chunk ^= row&7); ds_read applies the same involution.
#define STAGE(t, bufIdx)                                                              \
    {                                                                                 \
        _Pragma("unroll")                                                             \
        for (int j = 0; j < 8; ++j) {                                                 \
            const int q  = j * 64 + lane;      /* 16B-chunk index within tile */      \
            const int rr = q >> 5;             /* center row 0..15 */                 \
            const int cc = q & 31;             /* 16B chunk within row */             \
            const unsigned short* srcp =                                              \
                g_xb + (n0 + (t) * 16 + rr) * NM + ((cc ^ (rr & 7)) * 8);             \
            unsigned short* dstp = &Bt[w][bufIdx][j * 512];                           \
            __builtin_amdgcn_global_load_lds(                                         \
                (const __attribute__((address_space(1))) void*)srcp,                  \
                (__attribute__((address_space(3))) void*)dstp, 16, 0, 0);             \
        }                                                                             \
    }

// ---- A prologue helpers: NAMED fragments only (rule #20: no runtime-indexed arrays,
// the 4x8 short8 array version was demoted to scratch -> 66MB spill writes in R2/R3).
#define LOADFRAG(dst, s)                                                              \
    {                                                                                 \
        const float4 f0 = xr4[(s) * 8 + g * 2];                                       \
        const float4 f1 = xr4[(s) * 8 + g * 2 + 1];                                   \
        ss += f0.x * f0.x + f0.y * f0.y + f0.z * f0.z + f0.w * f0.w                   \
            + f1.x * f1.x + f1.y * f1.y + f1.z * f1.z + f1.w * f1.w;                  \
        short8 t;                                                                     \
        t[0] = (short)f2bf(f0.x); t[1] = (short)f2bf(f0.y);                           \
        t[2] = (short)f2bf(f0.z); t[3] = (short)f2bf(f0.w);                           \
        t[4] = (short)f2bf(f1.x); t[5] = (short)f2bf(f1.y);                           \
        t[6] = (short)f2bf(f1.z); t[7] = (short)f2bf(f1.w);                           \
        dst = t;                                                                      \
    }

#define LOADROW(rt, A0, A1, A2, A3, A4, A5, A6, A7)                                   \
    {                                                                                 \
        const float4* xr4 = (const float4*)(x + (row0 + (rt) * 16 + r) * NM);         \
        float ss = 0.f;                                                               \
        LOADFRAG(A0, 0) LOADFRAG(A1, 1) LOADFRAG(A2, 2) LOADFRAG(A3, 3)               \
        LOADFRAG(A4, 4) LOADFRAG(A5, 5) LOADFRAG(A6, 6) LOADFRAG(A7, 7)               \
        ss += __shfl_xor(ss, 16, 64);                                                 \
        ss += __shfl_xor(ss, 32, 64);                                                 \
        if (w == 0 && g == 0) xsl[(rt) * 16 + r] = ss * LOG2E;                        \
    }

// One K=32 step across all 4 row-tiles: 1 ds_read_b128 -> 4 MFMA. s must be a literal.
#define CSTEP(s)                                                                      \
    {                                                                                 \
        const short8 b =                                                              \
            *(const short8*)(bp + r * 256 + ((((s) * 4 + g) ^ (r & 7)) * 8));         \
        c0 = __builtin_amdgcn_mfma_f32_16x16x32_bf16(af0##s, b, c0, 0, 0, 0);         \
        c1 = __builtin_amdgcn_mfma_f32_16x16x32_bf16(af1##s, b, c1, 0, 0, 0);         \
        c2 = __builtin_amdgcn_mfma_f32_16x16x32_bf16(af2##s, b, c2, 0, 0, 0);         \
        c3 = __builtin_amdgcn_mfma_f32_16x16x32_bf16(af3##s, b, c3, 0, 0, 0);         \
    }

#define EPI1(cc, xsv, acref)                                                          \
    acref = fmaf(EXP2F(fmaf(cc, TWO_LOG2E, nb - (xsv))), wgt, acref);

// One 16-center tile: 8 ds_read_b128 -> 32 MFMA -> fused exp/W epilogue (all static).
#define COMPUTE(bufIdx, wcv)                                                          \
    {                                                                                 \
        const unsigned short* bp = &Bt[w][bufIdx][0];                                 \
        floatx4 c0 = {0.f, 0.f, 0.f, 0.f}, c1 = {0.f, 0.f, 0.f, 0.f};                 \
        floatx4 c2 = {0.f, 0.f, 0.f, 0.f}, c3 = {0.f, 0.f, 0.f, 0.f};                 \
        CSTEP(0) CSTEP(1) CSTEP(2) CSTEP(3) CSTEP(4) CSTEP(5) CSTEP(6) CSTEP(7)       \
        const float nb  = -(wcv).y;                                                   \
        const float wgt = (wcv).x;                                                    \
        EPI1(c0[0], xs0.x, ac0.x) EPI1(c0[1], xs0.y, ac0.y)                           \
        EPI1(c0[2], xs0.z, ac0.z) EPI1(c0[3], xs0.w, ac0.w)                           \
        EPI1(c1[0], xs1.x, ac1.x) EPI1(c1[1], xs1.y, ac1.y)                           \
        EPI1(c1[2], xs1.z, ac1.z) EPI1(c1[3], xs1.w, ac1.w)                           \
        EPI1(c2[0], xs2.x, ac2.x) EPI1(c2[1], xs2.y, ac2.y)                           \
        EPI1(c2[2], xs2.z, ac2.z) EPI1(c2[3], xs2.w, ac2.w)                           \
        EPI1(c3[0], xs3.x, ac3.x) EPI1(c3[1], xs3.y, ac3.y)                           \
        EPI1(c3[2], xs3.z, ac3.z) EPI1(c3[3], xs3.w, ac3.w)                           \
    }

#define RED(val, rt, j)                                                               \
    {                                                                                 \
        float v = (val);                                                              \
        v += __shfl_xor(v, 1, 64); v += __shfl_xor(v, 2, 64);                         \
        v += __shfl_xor(v, 4, 64); v += __shfl_xor(v, 8, 64);                         \
        if (r == 0) rowacc[w][(rt) * 16 + g * 4 + (j)] = v;                           \
    }

// 256 blocks (1/CU), 512 threads (8 waves). Block owns 64 rows; wave w owns ALL
// 4 row-tiles (A in 128 named-VGPR fragments) x centers [w*512, (w+1)*512).
// No main-loop barriers; per-wave counted vmcnt(9) double-buffer pipeline.
__global__ __launch_bounds__(512, 1) void rbf_main(const float* __restrict__ x,
                                                   const float* __restrict__ bptr,
                                                   float* __restrict__ out) {
    __shared__ __align__(16) unsigned short Bt[8][2][16 * NM];  // 128 KB
    __shared__ float xsl[64];
    __shared__ float rowacc[8][64];

    const int tid  = threadIdx.x;
    const int w    = tid >> 6;
    const int lane = tid & 63;
    const int r    = lane & 15;
    const int g    = lane >> 4;
    const int row0 = blockIdx.x * 64;
    const int n0   = w * 512;

    short8 af00, af01, af02, af03, af04, af05, af06, af07;
    short8 af10, af11, af12, af13, af14, af15, af16, af17;
    short8 af20, af21, af22, af23, af24, af25, af26, af27;
    short8 af30, af31, af32, af33, af34, af35, af36, af37;

    LOADROW(0, af00, af01, af02, af03, af04, af05, af06, af07)
    LOADROW(1, af10, af11, af12, af13, af14, af15, af16, af17)
    LOADROW(2, af20, af21, af22, af23, af24, af25, af26, af27)
    LOADROW(3, af30, af31, af32, af33, af34, af35, af36, af37)
    __syncthreads();

    // per-lane ||x||^2*log2e for this lane's C/D rows: rt*16 + g*4 + {0..3}
    const float4 xs0 = *(const float4*)&xsl[0 * 16 + g * 4];
    const float4 xs1 = *(const float4*)&xsl[1 * 16 + g * 4];
    const float4 xs2 = *(const float4*)&xsl[2 * 16 + g * 4];
    const float4 xs3 = *(const float4*)&xsl[3 * 16 + g * 4];

    float4 ac0 = {0.f, 0.f, 0.f, 0.f};
    float4 ac1 = {0.f, 0.f, 0.f, 0.f};
    float4 ac2 = {0.f, 0.f, 0.f, 0.f};
    float4 ac3 = {0.f, 0.f, 0.f, 0.f};

    // prologue: tile 0 + wc 0 in flight (9 vmem ops outstanding at loop top)
    STAGE(0, 0);
    float2 wcA = g_wc[n0 + r];
    float2 wcB;

    #pragma unroll 1
    for (int i = 0; i < 32; i += 2) {
        // ---- iter i: consume buf0/wcA, prefetch tile i+1 -> buf1 ----
        wcB = g_wc[n0 + ((i + 1) & 31) * 16 + r];
        STAGE((i + 1) & 31, 1);
        asm volatile("s_waitcnt vmcnt(9)" ::: "memory");  // tile i + wc_i drained
        __builtin_amdgcn_sched_barrier(0);
        COMPUTE(0, wcA);
        // ---- iter i+1: consume buf1/wcB, prefetch tile i+2 -> buf0 ----
        wcA = g_wc[n0 + ((i + 2) & 31) * 16 + r];
        STAGE((i + 2) & 31, 0);
        asm volatile("s_waitcnt vmcnt(9)" ::: "memory");
        __builtin_amdgcn_sched_barrier(0);
        COMPUTE(1, wcB);
    }

    // ---- reduce over the 16 column-lanes; combine 8 waves' N-partials ----
    RED(ac0.x, 0, 0) RED(ac0.y, 0, 1) RED(ac0.z, 0, 2) RED(ac0.w, 0, 3)
    RED(ac1.x, 1, 0) RED(ac1.y, 1, 1) RED(ac1.z, 1, 2) RED(ac1.w, 1, 3)
    RED(ac2.x, 2, 0) RED(ac2.y, 2, 1) RED(ac2.z, 2, 2) RED(ac2.w, 2, 3)
    RED(ac3.x, 3, 0) RED(ac3.y, 3, 1) RED(ac3.z, 3, 2) RED(ac3.w, 3, 3)
    __syncthreads();

    if (tid < 64) {
        float logit = bptr[0];
        #pragma unroll
        for (int ww = 0; ww < 8; ++ww) logit += rowacc[ww][tid];
        out[row0 + tid] = 1.f / (1.f + EXP2F(-logit * LOG2E));
    }
}

extern "C" void kernel_launch(void* const* d_in, const int* in_sizes, int n_in,
                              void* d_out, int out_size, void* d_ws, size_t ws_size,
                              hipStream_t stream) {
    const float* x  = (const float*)d_in[0];   // [16384,256]
    const float* xb = (const float*)d_in[1];   // [4096,256]
    const float* W  = (const float*)d_in[2];   // [1,4096]
    const float* b  = (const float*)d_in[3];   // [1]
    float* out = (float*)d_out;                // [16384,1]

    rbf_prep<<<dim3(NB / 4), dim3(256), 0, stream>>>(xb, W);
    rbf_main<<<dim3(NK / 64), dim3(512), 0, stream>>>(x, b, out);
}